// Round 16
// baseline (173.885 us; speedup 1.0000x reference)
//
#include <hip/hip_runtime.h>

// GraphConv pipeline v4 — same design as the v3 submission (which hit an
// infra "container failed twice"); symbols renamed to change the source
// hash.  Base = R14 clean bench (143.5 us total; fused 48 us, 60 VGPR).
// Delta vs R14: (1) no xT LDS staging — the GEMM epilogue reads x rows from
// global as float4 (L1 broadcast): LDS 38.4 -> 21.6 KB, lifting the static
// residency cap from 4 to 5-7 blocks/CU (the gather is concurrency-limited:
// occupancy 24%, FETCH 77 MB at only 1.9 TB/s).  (2) binner grid 512.
// Avoided constructs (spill history): __launch_bounds__ min-waves arg;
// aggressive unroll on the float4-staged epilogue loop.

#define FD 64      // feature dim (F_IN == F_OUT)
#define TN 64      // nodes per destination tile
#define BC 2048    // per-tile bucket capacity (mean 1024, ~32 sigma margin)
#define KP 65      // k-major LDS row stride (floats)
#define CS 16      // tile-counter stride: one counter per 64 B cache line
#define TM 1024    // binner LDS table capacity (tiles)
#define GB 512     // binner grid (2 blocks/CU)

// weight transpose (WT[k][o] = W[o][k]) fused with counter zeroing
__global__ __launch_bounds__(256) void gcv4_prep(
    const float* __restrict__ W_rel, const float* __restrict__ W_root,
    float* __restrict__ WTrel, float* __restrict__ WTroot,
    int* __restrict__ tcnt, int n_cnt) {
  const int idx = blockIdx.x * 256 + threadIdx.x;
  if (idx < FD * FD) {
    const int o = idx >> 6, k = idx & 63;
    WTrel[k * FD + o] = W_rel[idx];
    WTroot[k * FD + o] = W_root[idx];
  }
  for (int i = idx; i < n_cnt; i += gridDim.x * 256) tcnt[i] = 0;
}

// edge binner: per-block LDS histogram, single global atomic per
// (block,tile) to reserve a contiguous region, then dense packed writes.
// entry = dst<<16 | src (n_nodes = 50000 < 65536).
__global__ __launch_bounds__(256) void gcv4_bin(
    const int* __restrict__ eidx, int* __restrict__ tcnt,
    unsigned* __restrict__ tbuf, int n_edges, int n_tiles) {
  __shared__ int hcnt[TM];
  __shared__ int hbase[TM];

  const int t = threadIdx.x;
  for (int i = t; i < n_tiles; i += 256) hcnt[i] = 0;
  __syncthreads();

  const int per = (n_edges + gridDim.x - 1) / gridDim.x;
  const int e0 = blockIdx.x * per;
  const int e1 = min(e0 + per, n_edges);

  for (int e = e0 + t; e < e1; e += 256)
    atomicAdd(&hcnt[eidx[n_edges + e] >> 6], 1);
  __syncthreads();

  for (int i = t; i < n_tiles; i += 256) {
    const int c = hcnt[i];
    hbase[i] = (c > 0) ? atomicAdd(&tcnt[i * CS], c) : 0;
    hcnt[i] = 0;
  }
  __syncthreads();

  for (int e = e0 + t; e < e1; e += 256) {
    const int s = eidx[e];
    const int d = eidx[n_edges + e];
    const int tl = d >> 6;
    const int p = hbase[tl] + atomicAdd(&hcnt[tl], 1);
    if (p < BC)
      tbuf[(size_t)tl * BC + p] = ((unsigned)d << 16) | (unsigned)s;
  }
}

// per-tile fused kernel: counting sort -> atomic-free gather -> GEMM+ReLU
__global__ __launch_bounds__(256) void gcv4_main(
    const float* __restrict__ x,
    const float* __restrict__ WTrel,   // [FD][FD] k-major
    const float* __restrict__ b_rel,   // [FD]
    const float* __restrict__ WTroot,  // [FD][FD] k-major
    const int* __restrict__ tcnt,
    const unsigned* __restrict__ tbuf,
    float* __restrict__ out, int n_nodes) {
  __shared__ float aggT[FD * KP];          // k-major: aggT[k*KP + r]
  __shared__ unsigned short sl[BC + 64];   // dst-sorted src list (+pad)
  __shared__ int hh[TN];
  __shared__ int oo[TN + 1];
  __shared__ int cc[TN];

  const int t = threadIdx.x;
  const int lane = t & 63;
  const int w = t >> 6;
  const int tile = blockIdx.x;
  const int node0 = tile * TN;
  const int cnt = min(tcnt[tile * CS], BC);
  const unsigned* lst = tbuf + (size_t)tile * BC;

  // init: histogram zero + pad slots [cnt, cnt+64) of the src list
  if (t < TN) hh[t] = 0;
  if (t < 64 && cnt + t < BC + 64) sl[cnt + t] = 0;
  __syncthreads();

  // histogram over local dst
  for (int i = t; i < cnt; i += 256) atomicAdd(&hh[(lst[i] >> 16) & 63], 1);
  __syncthreads();

  // exclusive scan of the 64 counters (wave 0)
  if (w == 0) {
    int v = hh[lane];
    int s = v;
#pragma unroll
    for (int d = 1; d < 64; d <<= 1) {
      int u = __shfl_up(s, d, 64);
      if (lane >= d) s += u;
    }
    oo[lane] = s - v;
    cc[lane] = s - v;
    if (lane == 63) oo[64] = s;  // == cnt
  }
  __syncthreads();

  // counting-sort scatter
  for (int i = t; i < cnt; i += 256) {
    const unsigned e = lst[i];
    const int d = (int)((e >> 16) & 63);
    sl[atomicAdd(&cc[d], 1)] = (unsigned short)(e & 0xFFFFu);
  }
  __syncthreads();

  // gather: lanes = 4 edge-slots x 16 feature-quads, 4 float4 loads in
  // flight per lane, shfl_xor slot reduction, k-major aggT writes
  const int slot = lane >> 4;
  const int fq = lane & 15;
  for (int nn = 0; nn < 16; ++nn) {
    const int d = w * 16 + nn;
    const int jb = oo[d];
    const int je = oo[d + 1];
    float4 acc = make_float4(0.f, 0.f, 0.f, 0.f);
    const int i0 = slot, i1 = 4 + slot, i2 = 8 + slot, i3 = 12 + slot;
    for (int e0 = jb; e0 < je; e0 += 16) {
      const int m = je - e0;
      const int j0 = (i0 < m) ? e0 + i0 : cnt;  // pad entry -> src 0
      const int j1 = (i1 < m) ? e0 + i1 : cnt;
      const int j2 = (i2 < m) ? e0 + i2 : cnt;
      const int j3 = (i3 < m) ? e0 + i3 : cnt;
      const int s0 = (int)sl[j0];
      const int s1 = (int)sl[j1];
      const int s2 = (int)sl[j2];
      const int s3 = (int)sl[j3];
      const float4 f0 = *(const float4*)(x + (size_t)s0 * FD + fq * 4);
      const float4 f1 = *(const float4*)(x + (size_t)s1 * FD + fq * 4);
      const float4 f2 = *(const float4*)(x + (size_t)s2 * FD + fq * 4);
      const float4 f3 = *(const float4*)(x + (size_t)s3 * FD + fq * 4);
      acc.x += (i0 < m ? f0.x : 0.f); acc.y += (i0 < m ? f0.y : 0.f);
      acc.z += (i0 < m ? f0.z : 0.f); acc.w += (i0 < m ? f0.w : 0.f);
      acc.x += (i1 < m ? f1.x : 0.f); acc.y += (i1 < m ? f1.y : 0.f);
      acc.z += (i1 < m ? f1.z : 0.f); acc.w += (i1 < m ? f1.w : 0.f);
      acc.x += (i2 < m ? f2.x : 0.f); acc.y += (i2 < m ? f2.y : 0.f);
      acc.z += (i2 < m ? f2.z : 0.f); acc.w += (i2 < m ? f2.w : 0.f);
      acc.x += (i3 < m ? f3.x : 0.f); acc.y += (i3 < m ? f3.y : 0.f);
      acc.z += (i3 < m ? f3.z : 0.f); acc.w += (i3 < m ? f3.w : 0.f);
    }
    acc.x += __shfl_xor(acc.x, 16, 64); acc.y += __shfl_xor(acc.y, 16, 64);
    acc.z += __shfl_xor(acc.z, 16, 64); acc.w += __shfl_xor(acc.w, 16, 64);
    acc.x += __shfl_xor(acc.x, 32, 64); acc.y += __shfl_xor(acc.y, 32, 64);
    acc.z += __shfl_xor(acc.z, 32, 64); acc.w += __shfl_xor(acc.w, 32, 64);
    if (slot == 0) {
      aggT[(fq * 4 + 0) * KP + d] = acc.x;
      aggT[(fq * 4 + 1) * KP + d] = acc.y;
      aggT[(fq * 4 + 2) * KP + d] = acc.z;
      aggT[(fq * 4 + 3) * KP + d] = acc.w;
    }
  }
  __syncthreads();

  // GEMM epilogue: thread (rq,oq) owns 4x4 outputs.  aggT via broadcast
  // scalar LDS reads; x rows via float4 global reads (L1 broadcast, clamped
  // pointers for the tail tile; stores guarded).  unroll 2 keeps the live
  // float4 set bounded with no launch-bounds cap -> no spill.
  const int oq = t & 15, rq = t >> 4;
  const int o0 = oq * 4, r0 = rq * 4;
  const float* xp0 = x + (size_t)min(node0 + r0 + 0, n_nodes - 1) * FD;
  const float* xp1 = x + (size_t)min(node0 + r0 + 1, n_nodes - 1) * FD;
  const float* xp2 = x + (size_t)min(node0 + r0 + 2, n_nodes - 1) * FD;
  const float* xp3 = x + (size_t)min(node0 + r0 + 3, n_nodes - 1) * FD;
  const float4 bias = *(const float4*)(b_rel + o0);
  float acc[4][4];
#pragma unroll
  for (int ri = 0; ri < 4; ++ri) {
    acc[ri][0] = bias.x; acc[ri][1] = bias.y;
    acc[ri][2] = bias.z; acc[ri][3] = bias.w;
  }
#pragma unroll 2
  for (int k0 = 0; k0 < FD; k0 += 4) {
    const float4 q0 = *(const float4*)(xp0 + k0);
    const float4 q1 = *(const float4*)(xp1 + k0);
    const float4 q2 = *(const float4*)(xp2 + k0);
    const float4 q3 = *(const float4*)(xp3 + k0);
#pragma unroll
    for (int kk = 0; kk < 4; ++kk) {
      const int k = k0 + kk;
      const float4 wr = *(const float4*)(WTrel + k * FD + o0);
      const float4 wo = *(const float4*)(WTroot + k * FD + o0);
      const float a0 = aggT[k * KP + r0 + 0];
      const float a1 = aggT[k * KP + r0 + 1];
      const float a2 = aggT[k * KP + r0 + 2];
      const float a3 = aggT[k * KP + r0 + 3];
      const float x0 = ((const float*)&q0)[kk];
      const float x1 = ((const float*)&q1)[kk];
      const float x2 = ((const float*)&q2)[kk];
      const float x3 = ((const float*)&q3)[kk];
      acc[0][0] += a0 * wr.x + x0 * wo.x; acc[0][1] += a0 * wr.y + x0 * wo.y;
      acc[0][2] += a0 * wr.z + x0 * wo.z; acc[0][3] += a0 * wr.w + x0 * wo.w;
      acc[1][0] += a1 * wr.x + x1 * wo.x; acc[1][1] += a1 * wr.y + x1 * wo.y;
      acc[1][2] += a1 * wr.z + x1 * wo.z; acc[1][3] += a1 * wr.w + x1 * wo.w;
      acc[2][0] += a2 * wr.x + x2 * wo.x; acc[2][1] += a2 * wr.y + x2 * wo.y;
      acc[2][2] += a2 * wr.z + x2 * wo.z; acc[2][3] += a2 * wr.w + x2 * wo.w;
      acc[3][0] += a3 * wr.x + x3 * wo.x; acc[3][1] += a3 * wr.y + x3 * wo.y;
      acc[3][2] += a3 * wr.z + x3 * wo.z; acc[3][3] += a3 * wr.w + x3 * wo.w;
    }
  }
#pragma unroll
  for (int ri = 0; ri < 4; ++ri) {
    const int gi = node0 + r0 + ri;
    if (gi < n_nodes) {
      float4 o4;
      o4.x = fmaxf(acc[ri][0], 0.f); o4.y = fmaxf(acc[ri][1], 0.f);
      o4.z = fmaxf(acc[ri][2], 0.f); o4.w = fmaxf(acc[ri][3], 0.f);
      *(float4*)(out + (size_t)gi * FD + o0) = o4;
    }
  }
}

extern "C" void kernel_launch(void* const* d_in, const int* in_sizes, int n_in,
                              void* d_out, int out_size, void* d_ws, size_t ws_size,
                              hipStream_t stream) {
  const float* x      = (const float*)d_in[0];  // [N, 64]
  const float* W_rel  = (const float*)d_in[1];  // [64, 64]
  const float* b_rel  = (const float*)d_in[2];  // [64]
  const float* W_root = (const float*)d_in[3];  // [64, 64]
  const int* eidx     = (const int*)d_in[4];    // [2, E]

  const int n_nodes = in_sizes[0] / FD;
  const int n_edges = in_sizes[4] / 2;
  const int n_tiles = (n_nodes + TN - 1) / TN;  // 782

  int* tcnt      = (int*)d_ws;                                 // [n_tiles*CS]
  unsigned* tbuf = (unsigned*)(tcnt + (size_t)n_tiles * CS);   // [n_tiles*BC]
  float* WTrel   = (float*)(tbuf + (size_t)n_tiles * BC);
  float* WTroot  = WTrel + FD * FD;

  float* out = (float*)d_out;

  const int n_cnt = n_tiles * CS;
  const int gPrep = (n_cnt + 255) / 256;
  gcv4_prep<<<gPrep, 256, 0, stream>>>(W_rel, W_root, WTrel, WTroot, tcnt,
                                       n_cnt);

  gcv4_bin<<<GB, 256, 0, stream>>>(eidx, tcnt, tbuf, n_edges, n_tiles);

  gcv4_main<<<n_tiles, 256, 0, stream>>>(x, WTrel, b_rel, WTroot, tcnt, tbuf,
                                         out, n_nodes);
}

// Round 17
// 162.311 us; speedup vs baseline: 1.0713x; 1.0713x over previous
//
#include <hip/hip_runtime.h>

// GraphConv pipeline v5.
// R16 lesson: the fused grid (782 blocks) caps residency at ~3 blocks/CU, so
// shrinking LDS does nothing — and un-staging xT made phase E slower (64
// lane-duplicated L1 float4 loads/thread).  v5 = R14's proven internals
// (xT staged, k-major LDS, unroll-4 epilogue) with 512-thread blocks:
// 8 waves/block x ~3 blocks/CU = ~24 resident waves/CU (was 12).
// Avoided (history): __launch_bounds__ min-waves arg (spill), xT removal.

#define FD 64      // feature dim (F_IN == F_OUT)
#define TN 64      // nodes per destination tile
#define BC 2048    // per-tile bucket capacity (mean 1024, ~32 sigma margin)
#define KP 65      // k-major LDS row stride (floats)
#define CS 16      // tile-counter stride: one counter per 64 B line
#define TM 1024    // binner LDS table capacity (tiles)
#define GB 512     // binner grid (2 blocks/CU)

// weight transpose (WT[k][o] = W[o][k]) fused with counter zeroing
__global__ __launch_bounds__(256) void gcv5_prep(
    const float* __restrict__ W_rel, const float* __restrict__ W_root,
    float* __restrict__ WTrel, float* __restrict__ WTroot,
    int* __restrict__ tcnt, int n_cnt) {
  const int idx = blockIdx.x * 256 + threadIdx.x;
  if (idx < FD * FD) {
    const int o = idx >> 6, k = idx & 63;
    WTrel[k * FD + o] = W_rel[idx];
    WTroot[k * FD + o] = W_root[idx];
  }
  for (int i = idx; i < n_cnt; i += gridDim.x * 256) tcnt[i] = 0;
}

// edge binner: per-block LDS histogram -> one global atomic per
// (block,tile) region reservation -> dense packed writes.
// entry = dst<<16 | src (n_nodes = 50000 < 65536).
__global__ __launch_bounds__(256) void gcv5_bin(
    const int* __restrict__ eidx, int* __restrict__ tcnt,
    unsigned* __restrict__ tbuf, int n_edges, int n_tiles) {
  __shared__ int hcnt[TM];
  __shared__ int hbase[TM];

  const int t = threadIdx.x;
  for (int i = t; i < n_tiles; i += 256) hcnt[i] = 0;
  __syncthreads();

  const int per = (n_edges + gridDim.x - 1) / gridDim.x;
  const int e0 = blockIdx.x * per;
  const int e1 = min(e0 + per, n_edges);

  for (int e = e0 + t; e < e1; e += 256)
    atomicAdd(&hcnt[eidx[n_edges + e] >> 6], 1);
  __syncthreads();

  for (int i = t; i < n_tiles; i += 256) {
    const int c = hcnt[i];
    hbase[i] = (c > 0) ? atomicAdd(&tcnt[i * CS], c) : 0;
    hcnt[i] = 0;
  }
  __syncthreads();

  for (int e = e0 + t; e < e1; e += 256) {
    const int s = eidx[e];
    const int d = eidx[n_edges + e];
    const int tl = d >> 6;
    const int p = hbase[tl] + atomicAdd(&hcnt[tl], 1);
    if (p < BC)
      tbuf[(size_t)tl * BC + p] = ((unsigned)d << 16) | (unsigned)s;
  }
}

// per-tile fused kernel, 512 threads (8 waves):
// counting sort -> atomic-free dense gather -> GEMM + bias + ReLU
__global__ __launch_bounds__(512) void gcv5_main(
    const float* __restrict__ x,
    const float* __restrict__ WTrel,   // [FD][FD] k-major
    const float* __restrict__ b_rel,   // [FD]
    const float* __restrict__ WTroot,  // [FD][FD] k-major
    const int* __restrict__ tcnt,
    const unsigned* __restrict__ tbuf,
    float* __restrict__ out, int n_nodes) {
  __shared__ float aggT[FD * KP];          // k-major: aggT[k*KP + r]
  __shared__ float xT[FD * KP];            // k-major self tile
  __shared__ unsigned short sl[BC + 64];   // dst-sorted src list (+pad)
  __shared__ int hh[TN];
  __shared__ int oo[TN + 1];
  __shared__ int cc[TN];

  const int t = threadIdx.x;
  const int lane = t & 63;
  const int w = t >> 6;                  // wave 0..7
  const int tile = blockIdx.x;
  const int node0 = tile * TN;
  const int cnt = min(tcnt[tile * CS], BC);
  const unsigned* lst = tbuf + (size_t)tile * BC;

  // phase 0: zero histogram, zero src-list pad, stage xT (k-major)
  if (t < TN) hh[t] = 0;
  if (t < 64 && cnt + t < BC + 64) sl[cnt + t] = 0;
  {
    const int c4 = t & 15;       // feature quad 0..15
    const int rr = t >> 4;       // 0..31
#pragma unroll
    for (int p = 0; p < 2; ++p) {
      const int r = p * 32 + rr;
      const int gi = node0 + r;
      float4 v = make_float4(0.f, 0.f, 0.f, 0.f);
      if (gi < n_nodes) v = *(const float4*)(x + (size_t)gi * FD + c4 * 4);
      xT[(c4 * 4 + 0) * KP + r] = v.x;
      xT[(c4 * 4 + 1) * KP + r] = v.y;
      xT[(c4 * 4 + 2) * KP + r] = v.z;
      xT[(c4 * 4 + 3) * KP + r] = v.w;
    }
  }
  __syncthreads();

  // phase A: histogram by local dst (int LDS atomics, stride 512)
  for (int i = t; i < cnt; i += 512) atomicAdd(&hh[(lst[i] >> 16) & 63], 1);
  __syncthreads();

  // phase B: 64-wide exclusive scan in wave 0
  if (w == 0) {
    int v = hh[lane];
    int s = v;
#pragma unroll
    for (int d = 1; d < 64; d <<= 1) {
      int u = __shfl_up(s, d, 64);
      if (lane >= d) s += u;
    }
    oo[lane] = s - v;
    cc[lane] = s - v;
    if (lane == 63) oo[64] = s;  // == cnt
  }
  __syncthreads();

  // phase C: counting-sort scatter (stride 512)
  for (int i = t; i < cnt; i += 512) {
    const unsigned e = lst[i];
    const int d = (int)((e >> 16) & 63);
    sl[atomicAdd(&cc[d], 1)] = (unsigned short)(e & 0xFFFFu);
  }
  __syncthreads();

  // phase D: dense per-node gather; 8 waves x 8 nodes each;
  // lanes = 4 edge-slots x 16 feature-quads, 4 float4 loads in flight
  const int slot = lane >> 4;
  const int fq = lane & 15;
  for (int nn = 0; nn < 8; ++nn) {
    const int d = w * 8 + nn;
    const int jb = oo[d];
    const int je = oo[d + 1];
    float4 acc = make_float4(0.f, 0.f, 0.f, 0.f);
    const int i0 = slot, i1 = 4 + slot, i2 = 8 + slot, i3 = 12 + slot;
    for (int e0 = jb; e0 < je; e0 += 16) {
      const int m = je - e0;
      const int j0 = (i0 < m) ? e0 + i0 : cnt;  // pad entry -> src 0
      const int j1 = (i1 < m) ? e0 + i1 : cnt;
      const int j2 = (i2 < m) ? e0 + i2 : cnt;
      const int j3 = (i3 < m) ? e0 + i3 : cnt;
      const int s0 = (int)sl[j0];
      const int s1 = (int)sl[j1];
      const int s2 = (int)sl[j2];
      const int s3 = (int)sl[j3];
      const float4 f0 = *(const float4*)(x + (size_t)s0 * FD + fq * 4);
      const float4 f1 = *(const float4*)(x + (size_t)s1 * FD + fq * 4);
      const float4 f2 = *(const float4*)(x + (size_t)s2 * FD + fq * 4);
      const float4 f3 = *(const float4*)(x + (size_t)s3 * FD + fq * 4);
      acc.x += (i0 < m ? f0.x : 0.f); acc.y += (i0 < m ? f0.y : 0.f);
      acc.z += (i0 < m ? f0.z : 0.f); acc.w += (i0 < m ? f0.w : 0.f);
      acc.x += (i1 < m ? f1.x : 0.f); acc.y += (i1 < m ? f1.y : 0.f);
      acc.z += (i1 < m ? f1.z : 0.f); acc.w += (i1 < m ? f1.w : 0.f);
      acc.x += (i2 < m ? f2.x : 0.f); acc.y += (i2 < m ? f2.y : 0.f);
      acc.z += (i2 < m ? f2.z : 0.f); acc.w += (i2 < m ? f2.w : 0.f);
      acc.x += (i3 < m ? f3.x : 0.f); acc.y += (i3 < m ? f3.y : 0.f);
      acc.z += (i3 < m ? f3.z : 0.f); acc.w += (i3 < m ? f3.w : 0.f);
    }
    acc.x += __shfl_xor(acc.x, 16, 64); acc.y += __shfl_xor(acc.y, 16, 64);
    acc.z += __shfl_xor(acc.z, 16, 64); acc.w += __shfl_xor(acc.w, 16, 64);
    acc.x += __shfl_xor(acc.x, 32, 64); acc.y += __shfl_xor(acc.y, 32, 64);
    acc.z += __shfl_xor(acc.z, 32, 64); acc.w += __shfl_xor(acc.w, 32, 64);
    if (slot == 0) {
      aggT[(fq * 4 + 0) * KP + d] = acc.x;
      aggT[(fq * 4 + 1) * KP + d] = acc.y;
      aggT[(fq * 4 + 2) * KP + d] = acc.z;
      aggT[(fq * 4 + 3) * KP + d] = acc.w;
    }
  }
  __syncthreads();

  // phase E: thread (rq,oq) owns a 2x4 output block (512 threads cover
  // 64x64).  out[r][o] = relu(b[o] + sum_k aggT[k][r]*WTrel[k][o]
  //                                  + sum_k xT[k][r]*WTroot[k][o])
  const int oq = t & 15, rq = t >> 4;   // rq 0..31
  const int o0 = oq * 4, r0 = rq * 2;
  const float4 bias = *(const float4*)(b_rel + o0);
  float acc[2][4];
#pragma unroll
  for (int ri = 0; ri < 2; ++ri) {
    acc[ri][0] = bias.x; acc[ri][1] = bias.y;
    acc[ri][2] = bias.z; acc[ri][3] = bias.w;
  }
#pragma unroll 4
  for (int k = 0; k < FD; ++k) {
    const float4 wr = *(const float4*)(WTrel + k * FD + o0);
    const float4 wo = *(const float4*)(WTroot + k * FD + o0);
    const float a0 = aggT[k * KP + r0 + 0], a1 = aggT[k * KP + r0 + 1];
    const float x0 = xT[k * KP + r0 + 0], x1 = xT[k * KP + r0 + 1];
    acc[0][0] += a0 * wr.x + x0 * wo.x; acc[0][1] += a0 * wr.y + x0 * wo.y;
    acc[0][2] += a0 * wr.z + x0 * wo.z; acc[0][3] += a0 * wr.w + x0 * wo.w;
    acc[1][0] += a1 * wr.x + x1 * wo.x; acc[1][1] += a1 * wr.y + x1 * wo.y;
    acc[1][2] += a1 * wr.z + x1 * wo.z; acc[1][3] += a1 * wr.w + x1 * wo.w;
  }
#pragma unroll
  for (int ri = 0; ri < 2; ++ri) {
    const int gi = node0 + r0 + ri;
    if (gi < n_nodes) {
      float4 o4;
      o4.x = fmaxf(acc[ri][0], 0.f); o4.y = fmaxf(acc[ri][1], 0.f);
      o4.z = fmaxf(acc[ri][2], 0.f); o4.w = fmaxf(acc[ri][3], 0.f);
      *(float4*)(out + (size_t)gi * FD + o0) = o4;
    }
  }
}

extern "C" void kernel_launch(void* const* d_in, const int* in_sizes, int n_in,
                              void* d_out, int out_size, void* d_ws, size_t ws_size,
                              hipStream_t stream) {
  const float* x      = (const float*)d_in[0];  // [N, 64]
  const float* W_rel  = (const float*)d_in[1];  // [64, 64]
  const float* b_rel  = (const float*)d_in[2];  // [64]
  const float* W_root = (const float*)d_in[3];  // [64, 64]
  const int* eidx     = (const int*)d_in[4];    // [2, E]

  const int n_nodes = in_sizes[0] / FD;
  const int n_edges = in_sizes[4] / 2;
  const int n_tiles = (n_nodes + TN - 1) / TN;  // 782

  int* tcnt      = (int*)d_ws;                                 // [n_tiles*CS]
  unsigned* tbuf = (unsigned*)(tcnt + (size_t)n_tiles * CS);   // [n_tiles*BC]
  float* WTrel   = (float*)(tbuf + (size_t)n_tiles * BC);
  float* WTroot  = WTrel + FD * FD;

  float* out = (float*)d_out;

  const int n_cnt = n_tiles * CS;
  const int gPrep = (n_cnt + 255) / 256;
  gcv5_prep<<<gPrep, 256, 0, stream>>>(W_rel, W_root, WTrel, WTroot, tcnt,
                                       n_cnt);

  gcv5_bin<<<GB, 256, 0, stream>>>(eidx, tcnt, tbuf, n_edges, n_tiles);

  gcv5_main<<<n_tiles, 512, 0, stream>>>(x, WTrel, b_rel, WTroot, tcnt, tbuf,
                                         out, n_nodes);
}

// Round 18
// 145.964 us; speedup vs baseline: 1.1913x; 1.1120x over previous
//
#include <hip/hip_runtime.h>

// GraphConv pipeline v6.
// Base = R14 (proven: 143.5 us total, fused 48 us, 60 VGPR, 256 threads).
// R17 lesson: 512-thread blocks starve VGPRs (20!) and serialize the
// gather's in-flight loads; occupancy was never the binding constraint.
// v6 change: phase D processes TWO nodes per wave iteration, issuing both
// nodes' 4 float4 gathers back-to-back -> 8 loads in flight (double MLP).
// Everything else is R14 verbatim.  Avoided (history): launch_bounds
// min-waves arg (spill), 512-thread blocks (VGPR starvation), xT removal
// (L1 dup traffic).

#define FD 64      // feature dim (F_IN == F_OUT)
#define TN 64      // nodes per destination tile
#define BC 2048    // per-tile bucket capacity (mean 1024, ~32 sigma margin)
#define KP 65      // k-major LDS row stride (floats)
#define CS 16      // tile-counter stride: one counter per 64 B line
#define TM 1024    // binner LDS table capacity (tiles)
#define GB 256     // binner grid

// weight transpose (WT[k][o] = W[o][k]) fused with counter zeroing
__global__ __launch_bounds__(256) void gcv6_prep(
    const float* __restrict__ W_rel, const float* __restrict__ W_root,
    float* __restrict__ WTrel, float* __restrict__ WTroot,
    int* __restrict__ tcnt, int n_cnt) {
  const int idx = blockIdx.x * 256 + threadIdx.x;
  if (idx < FD * FD) {
    const int o = idx >> 6, k = idx & 63;
    WTrel[k * FD + o] = W_rel[idx];
    WTroot[k * FD + o] = W_root[idx];
  }
  for (int i = idx; i < n_cnt; i += gridDim.x * 256) tcnt[i] = 0;
}

// edge binner: per-block LDS histogram -> one global atomic per
// (block,tile) region reservation -> dense packed writes.
// entry = dst<<16 | src (n_nodes = 50000 < 65536).
__global__ __launch_bounds__(256) void gcv6_bin(
    const int* __restrict__ eidx, int* __restrict__ tcnt,
    unsigned* __restrict__ tbuf, int n_edges, int n_tiles) {
  __shared__ int hcnt[TM];
  __shared__ int hbase[TM];

  const int t = threadIdx.x;
  for (int i = t; i < n_tiles; i += 256) hcnt[i] = 0;
  __syncthreads();

  const int per = (n_edges + gridDim.x - 1) / gridDim.x;
  const int e0 = blockIdx.x * per;
  const int e1 = min(e0 + per, n_edges);

  for (int e = e0 + t; e < e1; e += 256)
    atomicAdd(&hcnt[eidx[n_edges + e] >> 6], 1);
  __syncthreads();

  for (int i = t; i < n_tiles; i += 256) {
    const int c = hcnt[i];
    hbase[i] = (c > 0) ? atomicAdd(&tcnt[i * CS], c) : 0;
    hcnt[i] = 0;
  }
  __syncthreads();

  for (int e = e0 + t; e < e1; e += 256) {
    const int s = eidx[e];
    const int d = eidx[n_edges + e];
    const int tl = d >> 6;
    const int p = hbase[tl] + atomicAdd(&hcnt[tl], 1);
    if (p < BC)
      tbuf[(size_t)tl * BC + p] = ((unsigned)d << 16) | (unsigned)s;
  }
}

// per-tile fused kernel (256 threads, 4 waves):
// counting sort -> atomic-free dense gather (2 nodes interleaved, 8 loads
// in flight) -> register-blocked GEMM + bias + ReLU
__global__ __launch_bounds__(256) void gcv6_main(
    const float* __restrict__ x,
    const float* __restrict__ WTrel,   // [FD][FD] k-major
    const float* __restrict__ b_rel,   // [FD]
    const float* __restrict__ WTroot,  // [FD][FD] k-major
    const int* __restrict__ tcnt,
    const unsigned* __restrict__ tbuf,
    float* __restrict__ out, int n_nodes) {
  __shared__ float aggT[FD * KP];          // k-major: aggT[k*KP + r]
  __shared__ float xT[FD * KP];            // k-major self tile
  __shared__ unsigned short sl[BC + 64];   // dst-sorted src list (+pad)
  __shared__ int hh[TN];
  __shared__ int oo[TN + 1];
  __shared__ int cc[TN];

  const int t = threadIdx.x;
  const int lane = t & 63;
  const int w = t >> 6;                  // wave 0..3
  const int tile = blockIdx.x;
  const int node0 = tile * TN;
  const int cnt = min(tcnt[tile * CS], BC);
  const unsigned* lst = tbuf + (size_t)tile * BC;

  // phase 0: zero histogram, zero src-list pad, stage xT (k-major)
  if (t < TN) hh[t] = 0;
  if (t < 64 && cnt + t < BC + 64) sl[cnt + t] = 0;
  {
    const int c4 = t & 15;       // feature quad 0..15
    const int rr = t >> 4;       // 0..15
#pragma unroll
    for (int p = 0; p < 4; ++p) {
      const int r = p * 16 + rr;
      const int gi = node0 + r;
      float4 v = make_float4(0.f, 0.f, 0.f, 0.f);
      if (gi < n_nodes) v = *(const float4*)(x + (size_t)gi * FD + c4 * 4);
      xT[(c4 * 4 + 0) * KP + r] = v.x;
      xT[(c4 * 4 + 1) * KP + r] = v.y;
      xT[(c4 * 4 + 2) * KP + r] = v.z;
      xT[(c4 * 4 + 3) * KP + r] = v.w;
    }
  }
  __syncthreads();

  // phase A: histogram by local dst (int LDS atomics)
  for (int i = t; i < cnt; i += 256) atomicAdd(&hh[(lst[i] >> 16) & 63], 1);
  __syncthreads();

  // phase B: 64-wide exclusive scan in wave 0
  if (w == 0) {
    int v = hh[lane];
    int s = v;
#pragma unroll
    for (int d = 1; d < 64; d <<= 1) {
      int u = __shfl_up(s, d, 64);
      if (lane >= d) s += u;
    }
    oo[lane] = s - v;
    cc[lane] = s - v;
    if (lane == 63) oo[64] = s;  // == cnt
  }
  __syncthreads();

  // phase C: counting-sort scatter
  for (int i = t; i < cnt; i += 256) {
    const unsigned e = lst[i];
    const int d = (int)((e >> 16) & 63);
    sl[atomicAdd(&cc[d], 1)] = (unsigned short)(e & 0xFFFFu);
  }
  __syncthreads();

  // phase D: dense gather, TWO nodes interleaved per iteration.
  // lanes = 4 edge-slots x 16 feature-quads; per iteration each lane
  // issues 4 float4 gathers for node A and 4 for node B back-to-back
  // (8 in flight), then accumulates both.  Exhausted/short chunks clamp
  // their sl index to the pad entry (src 0) and mask the adds.
  const int slot = lane >> 4;
  const int fq = lane & 15;
  const int i0 = slot, i1 = 4 + slot, i2 = 8 + slot, i3 = 12 + slot;
  for (int p = 0; p < 8; ++p) {
    const int dA = w * 16 + 2 * p;
    const int dB = dA + 1;
    int eA = oo[dA];
    const int eAend = oo[dA + 1];
    int eB = oo[dB];
    const int eBend = oo[dB + 1];
    float4 accA = make_float4(0.f, 0.f, 0.f, 0.f);
    float4 accB = make_float4(0.f, 0.f, 0.f, 0.f);
    while (eA < eAend || eB < eBend) {
      const int mA = eAend - eA;   // may be <= 0 (node exhausted)
      const int mB = eBend - eB;
      const int a0 = (i0 < mA) ? eA + i0 : cnt;
      const int a1 = (i1 < mA) ? eA + i1 : cnt;
      const int a2 = (i2 < mA) ? eA + i2 : cnt;
      const int a3 = (i3 < mA) ? eA + i3 : cnt;
      const int b0 = (i0 < mB) ? eB + i0 : cnt;
      const int b1 = (i1 < mB) ? eB + i1 : cnt;
      const int b2 = (i2 < mB) ? eB + i2 : cnt;
      const int b3 = (i3 < mB) ? eB + i3 : cnt;
      const int sA0 = (int)sl[a0], sA1 = (int)sl[a1];
      const int sA2 = (int)sl[a2], sA3 = (int)sl[a3];
      const int sB0 = (int)sl[b0], sB1 = (int)sl[b1];
      const int sB2 = (int)sl[b2], sB3 = (int)sl[b3];
      const float4 fA0 = *(const float4*)(x + (size_t)sA0 * FD + fq * 4);
      const float4 fA1 = *(const float4*)(x + (size_t)sA1 * FD + fq * 4);
      const float4 fA2 = *(const float4*)(x + (size_t)sA2 * FD + fq * 4);
      const float4 fA3 = *(const float4*)(x + (size_t)sA3 * FD + fq * 4);
      const float4 fB0 = *(const float4*)(x + (size_t)sB0 * FD + fq * 4);
      const float4 fB1 = *(const float4*)(x + (size_t)sB1 * FD + fq * 4);
      const float4 fB2 = *(const float4*)(x + (size_t)sB2 * FD + fq * 4);
      const float4 fB3 = *(const float4*)(x + (size_t)sB3 * FD + fq * 4);
      accA.x += (i0 < mA ? fA0.x : 0.f); accA.y += (i0 < mA ? fA0.y : 0.f);
      accA.z += (i0 < mA ? fA0.z : 0.f); accA.w += (i0 < mA ? fA0.w : 0.f);
      accA.x += (i1 < mA ? fA1.x : 0.f); accA.y += (i1 < mA ? fA1.y : 0.f);
      accA.z += (i1 < mA ? fA1.z : 0.f); accA.w += (i1 < mA ? fA1.w : 0.f);
      accA.x += (i2 < mA ? fA2.x : 0.f); accA.y += (i2 < mA ? fA2.y : 0.f);
      accA.z += (i2 < mA ? fA2.z : 0.f); accA.w += (i2 < mA ? fA2.w : 0.f);
      accA.x += (i3 < mA ? fA3.x : 0.f); accA.y += (i3 < mA ? fA3.y : 0.f);
      accA.z += (i3 < mA ? fA3.z : 0.f); accA.w += (i3 < mA ? fA3.w : 0.f);
      accB.x += (i0 < mB ? fB0.x : 0.f); accB.y += (i0 < mB ? fB0.y : 0.f);
      accB.z += (i0 < mB ? fB0.z : 0.f); accB.w += (i0 < mB ? fB0.w : 0.f);
      accB.x += (i1 < mB ? fB1.x : 0.f); accB.y += (i1 < mB ? fB1.y : 0.f);
      accB.z += (i1 < mB ? fB1.z : 0.f); accB.w += (i1 < mB ? fB1.w : 0.f);
      accB.x += (i2 < mB ? fB2.x : 0.f); accB.y += (i2 < mB ? fB2.y : 0.f);
      accB.z += (i2 < mB ? fB2.z : 0.f); accB.w += (i2 < mB ? fB2.w : 0.f);
      accB.x += (i3 < mB ? fB3.x : 0.f); accB.y += (i3 < mB ? fB3.y : 0.f);
      accB.z += (i3 < mB ? fB3.z : 0.f); accB.w += (i3 < mB ? fB3.w : 0.f);
      eA += 16;
      eB += 16;
    }
    // slot reduction for both nodes
    accA.x += __shfl_xor(accA.x, 16, 64); accA.y += __shfl_xor(accA.y, 16, 64);
    accA.z += __shfl_xor(accA.z, 16, 64); accA.w += __shfl_xor(accA.w, 16, 64);
    accB.x += __shfl_xor(accB.x, 16, 64); accB.y += __shfl_xor(accB.y, 16, 64);
    accB.z += __shfl_xor(accB.z, 16, 64); accB.w += __shfl_xor(accB.w, 16, 64);
    accA.x += __shfl_xor(accA.x, 32, 64); accA.y += __shfl_xor(accA.y, 32, 64);
    accA.z += __shfl_xor(accA.z, 32, 64); accA.w += __shfl_xor(accA.w, 32, 64);
    accB.x += __shfl_xor(accB.x, 32, 64); accB.y += __shfl_xor(accB.y, 32, 64);
    accB.z += __shfl_xor(accB.z, 32, 64); accB.w += __shfl_xor(accB.w, 32, 64);
    if (slot == 0) {
      aggT[(fq * 4 + 0) * KP + dA] = accA.x;
      aggT[(fq * 4 + 1) * KP + dA] = accA.y;
      aggT[(fq * 4 + 2) * KP + dA] = accA.z;
      aggT[(fq * 4 + 3) * KP + dA] = accA.w;
      aggT[(fq * 4 + 0) * KP + dB] = accB.x;
      aggT[(fq * 4 + 1) * KP + dB] = accB.y;
      aggT[(fq * 4 + 2) * KP + dB] = accB.z;
      aggT[(fq * 4 + 3) * KP + dB] = accB.w;
    }
  }
  __syncthreads();

  // phase E: out[r][o] = relu(b[o] + sum_k aggT[k][r]*WTrel[k][o]
  //                                  + sum_k xT[k][r]*WTroot[k][o])
  // R14-verbatim: 4x4 blocking, broadcast scalar LDS reads, unroll 4.
  const int oq = t & 15, rq = t >> 4;
  const int o0 = oq * 4, r0 = rq * 4;
  const float4 bias = *(const float4*)(b_rel + o0);
  float acc[4][4];
#pragma unroll
  for (int ri = 0; ri < 4; ++ri) {
    acc[ri][0] = bias.x; acc[ri][1] = bias.y;
    acc[ri][2] = bias.z; acc[ri][3] = bias.w;
  }
#pragma unroll 4
  for (int k = 0; k < FD; ++k) {
    const float4 wr = *(const float4*)(WTrel + k * FD + o0);
    const float4 wo = *(const float4*)(WTroot + k * FD + o0);
    const float a0 = aggT[k * KP + r0 + 0], a1 = aggT[k * KP + r0 + 1];
    const float a2 = aggT[k * KP + r0 + 2], a3 = aggT[k * KP + r0 + 3];
    const float x0 = xT[k * KP + r0 + 0], x1 = xT[k * KP + r0 + 1];
    const float x2 = xT[k * KP + r0 + 2], x3 = xT[k * KP + r0 + 3];
    acc[0][0] += a0 * wr.x + x0 * wo.x; acc[0][1] += a0 * wr.y + x0 * wo.y;
    acc[0][2] += a0 * wr.z + x0 * wo.z; acc[0][3] += a0 * wr.w + x0 * wo.w;
    acc[1][0] += a1 * wr.x + x1 * wo.x; acc[1][1] += a1 * wr.y + x1 * wo.y;
    acc[1][2] += a1 * wr.z + x1 * wo.z; acc[1][3] += a1 * wr.w + x1 * wo.w;
    acc[2][0] += a2 * wr.x + x2 * wo.x; acc[2][1] += a2 * wr.y + x2 * wo.y;
    acc[2][2] += a2 * wr.z + x2 * wo.z; acc[2][3] += a2 * wr.w + x2 * wo.w;
    acc[3][0] += a3 * wr.x + x3 * wo.x; acc[3][1] += a3 * wr.y + x3 * wo.y;
    acc[3][2] += a3 * wr.z + x3 * wo.z; acc[3][3] += a3 * wr.w + x3 * wo.w;
  }
#pragma unroll
  for (int ri = 0; ri < 4; ++ri) {
    const int gi = node0 + r0 + ri;
    if (gi < n_nodes) {
      float4 o4;
      o4.x = fmaxf(acc[ri][0], 0.f); o4.y = fmaxf(acc[ri][1], 0.f);
      o4.z = fmaxf(acc[ri][2], 0.f); o4.w = fmaxf(acc[ri][3], 0.f);
      *(float4*)(out + (size_t)gi * FD + o0) = o4;
    }
  }
}

extern "C" void kernel_launch(void* const* d_in, const int* in_sizes, int n_in,
                              void* d_out, int out_size, void* d_ws, size_t ws_size,
                              hipStream_t stream) {
  const float* x      = (const float*)d_in[0];  // [N, 64]
  const float* W_rel  = (const float*)d_in[1];  // [64, 64]
  const float* b_rel  = (const float*)d_in[2];  // [64]
  const float* W_root = (const float*)d_in[3];  // [64, 64]
  const int* eidx     = (const int*)d_in[4];    // [2, E]

  const int n_nodes = in_sizes[0] / FD;
  const int n_edges = in_sizes[4] / 2;
  const int n_tiles = (n_nodes + TN - 1) / TN;  // 782

  int* tcnt      = (int*)d_ws;                                 // [n_tiles*CS]
  unsigned* tbuf = (unsigned*)(tcnt + (size_t)n_tiles * CS);   // [n_tiles*BC]
  float* WTrel   = (float*)(tbuf + (size_t)n_tiles * BC);
  float* WTroot  = WTrel + FD * FD;

  float* out = (float*)d_out;

  const int n_cnt = n_tiles * CS;
  const int gPrep = (n_cnt + 255) / 256;
  gcv6_prep<<<gPrep, 256, 0, stream>>>(W_rel, W_root, WTrel, WTroot, tcnt,
                                       n_cnt);

  gcv6_bin<<<GB, 256, 0, stream>>>(eidx, tcnt, tbuf, n_edges, n_tiles);

  gcv6_main<<<n_tiles, 256, 0, stream>>>(x, WTrel, b_rel, WTroot, tcnt, tbuf,
                                         out, n_nodes);
}